// Round 11
// baseline (354.165 us; speedup 1.0000x reference)
//
#include <hip/hip_runtime.h>

typedef unsigned short ushort_t;
typedef unsigned int uint_t;

// ---------------------------------------------------------------------------
// GCN 3-layer forward.  N=50000, E=800000, D=H=128, C=40.
// Round 11: (1) csr entries 8B -> 4B (src only; w = dinv[src]*dinv[dst]
// recomputed in agg — bitwise-identical product).  Halves k_fill's random
// scatter (R10: 53 MB WRITE for 6.4 MB payload) and the csr stream in all
// agg passes.  (2) agg128 sliced 2-way at FULL-LINE granularity: half-wave
// gathers one aligned 128-B line (64 bf16 features, ushort2/lane); slice 0
// -> XCDs 0-3, slice 1 -> XCDs 4-7 via blockIdx&7.  Per-XCD working set
// 12.8 -> 6.4 MB, device gather fetch ~102 -> ~51 MB.  Degrades to neutral
// if the XCD mapping heuristic is wrong (bytes/edge unchanged).
// ws layout: [deg:N int][rowptr:N+1 int][cursor:N int][dinv:N f32][bsum:1024 int]
//            [csr:E int (src)][bufA:N*128*4 B][bufB:N*128 f32]
// ---------------------------------------------------------------------------

__global__ void k_deg_count(const int* __restrict__ ei, int* __restrict__ deg, int E) {
    int e = blockIdx.x * blockDim.x + threadIdx.x;
    if (e < E) atomicAdd(&deg[ei[E + e]], 1);   // dst = ei[E+e]
}

__global__ void k_bsum(const int* __restrict__ deg, int* __restrict__ bsum, int n) {
    __shared__ int s[256];
    int t = threadIdx.x;
    int i = blockIdx.x * 256 + t;
    s[t] = (i < n) ? deg[i] : 0;
    __syncthreads();
    for (int off = 128; off > 0; off >>= 1) {
        if (t < off) s[t] += s[t + off];
        __syncthreads();
    }
    if (t == 0) bsum[blockIdx.x] = s[0];
}

__global__ void k_bscan(int* __restrict__ bsum, int* __restrict__ tot, int nb) {
    __shared__ int s[1024];
    int t = threadIdx.x;
    int v = (t < nb) ? bsum[t] : 0;
    s[t] = v;
    __syncthreads();
    for (int off = 1; off < 1024; off <<= 1) {
        int u = (t >= off) ? s[t - off] : 0;
        __syncthreads();
        s[t] += u;
        __syncthreads();
    }
    if (t < nb) bsum[t] = s[t] - v;
    if (t == nb - 1) tot[0] = s[t];
}

__global__ void k_rowptr(const int* __restrict__ deg, const int* __restrict__ bsum,
                         int* __restrict__ rowptr, int* __restrict__ cursor,
                         float* __restrict__ dinv, int n) {
    __shared__ int s[256];
    int t = threadIdx.x;
    int i = blockIdx.x * 256 + t;
    int v = (i < n) ? deg[i] : 0;
    s[t] = v;
    __syncthreads();
    for (int off = 1; off < 256; off <<= 1) {
        int u = (t >= off) ? s[t - off] : 0;
        __syncthreads();
        s[t] += u;
        __syncthreads();
    }
    if (i < n) {
        int ex = bsum[blockIdx.x] + s[t] - v;
        rowptr[i] = ex;
        cursor[i] = ex;
        dinv[i] = rsqrtf((float)(v + 1));   // +1 self-loop
    }
}

// csr[pos] = src (4 B); weight recomputed in agg from dinv.
__global__ void k_fill(const int* __restrict__ ei, int* __restrict__ cursor,
                       int* __restrict__ csr, int E) {
    int e = blockIdx.x * blockDim.x + threadIdx.x;
    if (e >= E) return;
    int s = ei[e];
    int d = ei[E + e];
    int pos = atomicAdd(&cursor[d], 1);
    csr[pos] = s;
}

__device__ __forceinline__ ushort_t f2bf_rne(float f) {
    uint_t u = __float_as_uint(f);
    u += 0x7fffu + ((u >> 16) & 1u);
    return (ushort_t)(u >> 16);
}
__device__ __forceinline__ float bf2f(ushort_t h) {
    return __uint_as_float((uint_t)h << 16);
}
__device__ __forceinline__ float bflo(uint_t u) {
    return __uint_as_float(u << 16);
}
__device__ __forceinline__ float bfhi(uint_t u) {
    return __uint_as_float(u & 0xffff0000u);
}

// ---- Ybf16[N,128] = X[N,128] @ W[128,128].  BM=64, BK=32; 4x8 microtile.
__global__ __launch_bounds__(256) void k_gemm128(const float* __restrict__ X,
                                                 const float* __restrict__ W,
                                                 ushort_t* __restrict__ Y, int N) {
    __shared__ float sX[32][68];
    __shared__ float sW[32][128];
    const int tid = threadIdx.x;
    const int bm = blockIdx.x * 64;
    const int m0 = (tid >> 4) * 4;   // 0..60
    const int c4 = (tid & 15) * 4;   // 0..60
    const int xr = tid >> 3;
    const int xf = tid & 7;
    float acc[4][8] = {};
    for (int k0 = 0; k0 < 128; k0 += 32) {
        #pragma unroll
        for (int rr = 0; rr < 2; ++rr) {
            int row = bm + xr + rr * 32;
            int rc = min(row, N - 1);
            float4 v = *(const float4*)(X + (size_t)rc * 128 + k0 + xf * 4);
            int m = xr + rr * 32;
            sX[xf * 4 + 0][m] = v.x;
            sX[xf * 4 + 1][m] = v.y;
            sX[xf * 4 + 2][m] = v.z;
            sX[xf * 4 + 3][m] = v.w;
        }
        #pragma unroll
        for (int it = 0; it < 4; ++it) {
            int i = tid + it * 256;
            int wr = i >> 5;
            int wf = i & 31;
            *(float4*)(&sW[wr][wf * 4]) =
                *(const float4*)(W + (size_t)(k0 + wr) * 128 + wf * 4);
        }
        __syncthreads();
        #pragma unroll
        for (int kk = 0; kk < 32; ++kk) {
            float4 a  = *(const float4*)(&sX[kk][m0]);
            float4 b0 = *(const float4*)(&sW[kk][c4]);
            float4 b1 = *(const float4*)(&sW[kk][64 + c4]);
            float av[4] = {a.x, a.y, a.z, a.w};
            float bv[8] = {b0.x, b0.y, b0.z, b0.w, b1.x, b1.y, b1.z, b1.w};
            #pragma unroll
            for (int r = 0; r < 4; ++r)
                #pragma unroll
                for (int c = 0; c < 8; ++c)
                    acc[r][c] = fmaf(av[r], bv[c], acc[r][c]);
        }
        __syncthreads();
    }
    #pragma unroll
    for (int r = 0; r < 4; ++r) {
        int row = bm + m0 + r;
        if (row < N) {
            ushort4 o0 = {f2bf_rne(acc[r][0]), f2bf_rne(acc[r][1]),
                          f2bf_rne(acc[r][2]), f2bf_rne(acc[r][3])};
            ushort4 o1 = {f2bf_rne(acc[r][4]), f2bf_rne(acc[r][5]),
                          f2bf_rne(acc[r][6]), f2bf_rne(acc[r][7])};
            *(ushort4*)(Y + (size_t)row * 128 + c4)      = o0;
            *(ushort4*)(Y + (size_t)row * 128 + 64 + c4) = o1;
        }
    }
}

// ---- Ybf16[N,40 (stride 64)] = X[N,128] @ W[128,40].  BM=128, BK=32. ----
__global__ __launch_bounds__(256) void k_gemm40(const float* __restrict__ X,
                                                const float* __restrict__ W,
                                                ushort_t* __restrict__ Y, int N) {
    __shared__ float sX[32][132];
    __shared__ float sW[32][40];
    const int tid = threadIdx.x;
    const int bm = blockIdx.x * 128;
    const int m0 = (tid >> 3) * 4;
    const int n0 = (tid & 7) * 5;
    const int xf = tid & 7;
    float acc[4][5] = {};
    for (int k0 = 0; k0 < 128; k0 += 32) {
        #pragma unroll
        for (int it = 0; it < 4; ++it) {
            int i = tid + it * 256;
            int row = bm + (i >> 3);
            int rc = min(row, N - 1);
            float4 v = *(const float4*)(X + (size_t)rc * 128 + k0 + xf * 4);
            int m = i >> 3;
            sX[xf * 4 + 0][m] = v.x;
            sX[xf * 4 + 1][m] = v.y;
            sX[xf * 4 + 2][m] = v.z;
            sX[xf * 4 + 3][m] = v.w;
        }
        for (int i = tid; i < 320; i += 256) {
            int wr = i / 10;
            int wf = i - wr * 10;
            *(float4*)(&sW[wr][wf * 4]) =
                *(const float4*)(W + (size_t)(k0 + wr) * 40 + wf * 4);
        }
        __syncthreads();
        #pragma unroll
        for (int kk = 0; kk < 32; ++kk) {
            float4 a = *(const float4*)(&sX[kk][m0]);
            float av[4] = {a.x, a.y, a.z, a.w};
            #pragma unroll
            for (int c = 0; c < 5; ++c) {
                float b = sW[kk][n0 + c];
                #pragma unroll
                for (int r = 0; r < 4; ++r)
                    acc[r][c] = fmaf(av[r], b, acc[r][c]);
            }
        }
        __syncthreads();
    }
    #pragma unroll
    for (int r = 0; r < 4; ++r) {
        int row = bm + m0 + r;
        if (row < N) {
            #pragma unroll
            for (int c = 0; c < 5; ++c)
                Y[(size_t)row * 64 + n0 + c] = f2bf_rne(acc[r][c]);
        }
    }
}

// Sliced agg, F=128 bf16.  Half-wave handles (dst, 64-feature slice) = one
// aligned 128-B line per gather (ushort2/lane).  slice = (blockIdx&7)>>2
// rides round-robin XCD dispatch: XCDs 0-3 see only slice 0, 4-7 slice 1.
// w = dinv[src]*dinv[dst] recomputed (bitwise-identical to stored form).
template <bool RELU>
__global__ __launch_bounds__(256) void k_agg128(
        const ushort_t* __restrict__ XW, const int* __restrict__ rowptr,
        const int* __restrict__ csr, const float* __restrict__ dinv,
        const float* __restrict__ bias, float* __restrict__ out, int n) {
    const int lane = threadIdx.x & 31;
    const int sub  = threadIdx.x >> 5;              // 8 half-waves/block
    const int g = blockIdx.x;
    const int xcd = g & 7;
    const int slice = xcd >> 2;                     // 0 on XCD0-3, 1 on XCD4-7
    const int pair = (g >> 3) * 4 + (xcd & 3);      // dst-group index
    const int d = pair * 8 + sub;
    if (d >= n) return;
    const uint_t* xw = (const uint_t*)XW;           // ushort2 as uint; row stride 64
    const int fb = slice * 32 + lane;               // uint index within row
    float dv = dinv[d];
    float w0 = dv * dv;
    uint_t sq = xw[(size_t)d * 64 + fb];
    float2 a;
    a.x = w0 * bflo(sq);
    a.y = w0 * bfhi(sq);
    int j = rowptr[d], end = rowptr[d + 1];
    for (; j + 8 <= end; j += 8) {
        int s0 = csr[j + 0], s1 = csr[j + 1], s2 = csr[j + 2], s3 = csr[j + 3];
        int s4 = csr[j + 4], s5 = csr[j + 5], s6 = csr[j + 6], s7 = csr[j + 7];
        float w0e = dinv[s0] * dv, w1e = dinv[s1] * dv;
        float w2e = dinv[s2] * dv, w3e = dinv[s3] * dv;
        float w4e = dinv[s4] * dv, w5e = dinv[s5] * dv;
        float w6e = dinv[s6] * dv, w7e = dinv[s7] * dv;
        uint_t u0 = xw[(size_t)s0 * 64 + fb];
        uint_t u1 = xw[(size_t)s1 * 64 + fb];
        uint_t u2 = xw[(size_t)s2 * 64 + fb];
        uint_t u3 = xw[(size_t)s3 * 64 + fb];
        uint_t u4 = xw[(size_t)s4 * 64 + fb];
        uint_t u5 = xw[(size_t)s5 * 64 + fb];
        uint_t u6 = xw[(size_t)s6 * 64 + fb];
        uint_t u7 = xw[(size_t)s7 * 64 + fb];
        a.x = fmaf(w0e, bflo(u0), a.x); a.y = fmaf(w0e, bfhi(u0), a.y);
        a.x = fmaf(w1e, bflo(u1), a.x); a.y = fmaf(w1e, bfhi(u1), a.y);
        a.x = fmaf(w2e, bflo(u2), a.x); a.y = fmaf(w2e, bfhi(u2), a.y);
        a.x = fmaf(w3e, bflo(u3), a.x); a.y = fmaf(w3e, bfhi(u3), a.y);
        a.x = fmaf(w4e, bflo(u4), a.x); a.y = fmaf(w4e, bfhi(u4), a.y);
        a.x = fmaf(w5e, bflo(u5), a.x); a.y = fmaf(w5e, bfhi(u5), a.y);
        a.x = fmaf(w6e, bflo(u6), a.x); a.y = fmaf(w6e, bfhi(u6), a.y);
        a.x = fmaf(w7e, bflo(u7), a.x); a.y = fmaf(w7e, bfhi(u7), a.y);
    }
    for (; j < end; ++j) {
        int s = csr[j];
        float we = dinv[s] * dv;
        uint_t u = xw[(size_t)s * 64 + fb];
        a.x = fmaf(we, bflo(u), a.x);
        a.y = fmaf(we, bfhi(u), a.y);
    }
    float2 b = ((const float2*)bias)[fb];
    a.x += b.x; a.y += b.y;
    if (RELU) {
        a.x = fmaxf(a.x, 0.f);
        a.y = fmaxf(a.y, 0.f);
    }
    ((float2*)out)[(size_t)d * 64 + fb] = a;
}

// Half-wave per dst, F=40 bf16 rows padded to stride 64 (one 128-B line):
// lanes 0..19 hold ushort2; fp32 accumulate; fp32 output.
__global__ __launch_bounds__(256) void k_agg40(
        const ushort_t* __restrict__ XW, const int* __restrict__ rowptr,
        const int* __restrict__ csr, const float* __restrict__ dinv,
        const float* __restrict__ bias, float* __restrict__ out, int n) {
    const int lane = threadIdx.x & 31;
    const int sub  = threadIdx.x >> 5;
    const int d = blockIdx.x * 8 + sub;
    if (d >= n || lane >= 20) return;
    const uint_t* xw = (const uint_t*)XW;       // row stride 32 uints
    float dv = dinv[d];
    float w0 = dv * dv;
    uint_t sq = xw[(size_t)d * 32 + lane];
    float2 a;
    a.x = w0 * bflo(sq);
    a.y = w0 * bfhi(sq);
    int j = rowptr[d], end = rowptr[d + 1];
    for (; j + 4 <= end; j += 4) {
        int s0 = csr[j + 0], s1 = csr[j + 1], s2 = csr[j + 2], s3 = csr[j + 3];
        float w0e = dinv[s0] * dv, w1e = dinv[s1] * dv;
        float w2e = dinv[s2] * dv, w3e = dinv[s3] * dv;
        uint_t u0 = xw[(size_t)s0 * 32 + lane];
        uint_t u1 = xw[(size_t)s1 * 32 + lane];
        uint_t u2 = xw[(size_t)s2 * 32 + lane];
        uint_t u3 = xw[(size_t)s3 * 32 + lane];
        a.x = fmaf(w0e, bflo(u0), a.x); a.y = fmaf(w0e, bfhi(u0), a.y);
        a.x = fmaf(w1e, bflo(u1), a.x); a.y = fmaf(w1e, bfhi(u1), a.y);
        a.x = fmaf(w2e, bflo(u2), a.x); a.y = fmaf(w2e, bfhi(u2), a.y);
        a.x = fmaf(w3e, bflo(u3), a.x); a.y = fmaf(w3e, bfhi(u3), a.y);
    }
    for (; j < end; ++j) {
        int s = csr[j];
        float we = dinv[s] * dv;
        uint_t u = xw[(size_t)s * 32 + lane];
        a.x = fmaf(we, bflo(u), a.x);
        a.y = fmaf(we, bfhi(u), a.y);
    }
    float2 b = ((const float2*)bias)[lane];
    a.x += b.x; a.y += b.y;
    ((float2*)out)[(size_t)d * 20 + lane] = a;
}

static inline int cdiv(long long a, int b) { return (int)((a + b - 1) / b); }

extern "C" void kernel_launch(void* const* d_in, const int* in_sizes, int n_in,
                              void* d_out, int out_size, void* d_ws, size_t ws_size,
                              hipStream_t stream) {
    const float* x  = (const float*)d_in[0];
    const int*   ei = (const int*)d_in[1];
    const float* W1 = (const float*)d_in[2];
    const float* b1 = (const float*)d_in[3];
    const float* W2 = (const float*)d_in[4];
    const float* b2 = (const float*)d_in[5];
    const float* W3 = (const float*)d_in[6];
    const float* b3 = (const float*)d_in[7];
    float* out = (float*)d_out;

    const int N = in_sizes[0] / 128;   // 50000
    const int E = in_sizes[1] / 2;     // 800000

    char* ws = (char*)d_ws;
    int*   deg    = (int*)ws;                 ws += (size_t)N * 4;
    int*   rowptr = (int*)ws;                 ws += (size_t)(N + 1) * 4;
    int*   cursor = (int*)ws;                 ws += (size_t)N * 4;
    float* dinv   = (float*)ws;               ws += (size_t)N * 4;
    int*   bsum   = (int*)ws;                 ws += (size_t)1024 * 4;
    ws = (char*)(((uintptr_t)ws + 127) & ~(uintptr_t)127);
    int*   csr    = (int*)ws;                 ws += (size_t)E * 4;       // 3.2 MB, 128-B aligned
    char*  bufA   = ws;                       ws += (size_t)N * 128 * 4; // bf16 XW / bf16 XW40
    float* bufB   = (float*)ws;

    const int BT = 256;
    const int nb = cdiv(N, 256);
    const int ndg = cdiv(N, 8);                       // dst-groups of 8
    const int agg128Grid = cdiv(ndg, 4) * 8;          // 4 dst-groups x 2 slices per 8 blocks

    // CSR build (per call; no state survives between calls)
    hipMemsetAsync(deg, 0, (size_t)N * 4, stream);
    k_deg_count<<<cdiv(E, BT), BT, 0, stream>>>(ei, deg, E);
    k_bsum<<<nb, 256, 0, stream>>>(deg, bsum, N);
    k_bscan<<<1, 1024, 0, stream>>>(bsum, rowptr + N, nb);
    k_rowptr<<<nb, 256, 0, stream>>>(deg, bsum, rowptr, cursor, dinv, N);
    k_fill<<<cdiv(E, BT), BT, 0, stream>>>(ei, cursor, csr, E);

    // layer 1
    k_gemm128<<<cdiv(N, 64), 256, 0, stream>>>(x, W1, (ushort_t*)bufA, N);
    k_agg128<true><<<agg128Grid, 256, 0, stream>>>((const ushort_t*)bufA, rowptr, csr, dinv, b1, bufB, N);
    // layer 2
    k_gemm128<<<cdiv(N, 64), 256, 0, stream>>>(bufB, W2, (ushort_t*)bufA, N);
    k_agg128<true><<<agg128Grid, 256, 0, stream>>>((const ushort_t*)bufA, rowptr, csr, dinv, b2, bufB, N);
    // layer 3 (bf16 staged, rows padded to one 128-B line)
    k_gemm40<<<cdiv(N, 128), 256, 0, stream>>>(bufB, W3, (ushort_t*)bufA, N);
    k_agg40<<<cdiv(N, 8), 256, 0, stream>>>((const ushort_t*)bufA, rowptr, csr, dinv, b3, out, N);
}

// Round 12
// 342.458 us; speedup vs baseline: 1.0342x; 1.0342x over previous
//
#include <hip/hip_runtime.h>

typedef unsigned short ushort_t;
typedef unsigned int uint_t;

// ---------------------------------------------------------------------------
// GCN 3-layer forward.  N=50000, E=800000, D=H=128, C=40.
// Round 12: XCD-partitioned k_fill.  R11 showed fill's 52.7 MB WRITE (for a
// 3.2 MB csr payload) is cross-XCD line ping-pong: csr is dst-ordered and all
// 8 XCDs scatter into the whole range.  Now block b serves dst-range
// [(b&7)*N/8, ...): each contiguous csr span is written by ONE XCD ->
// lines coalesce in its L2 and write back once.  Edge stream read 8x
// (L3-served).  agg128 2-way slice + 4B csr + bf16 staging kept from R9-R11.
// ws layout: [deg:N int][rowptr:N+1 int][cursor:N int][dinv:N f32][bsum:1024 int]
//            [csr:E int (src)][bufA:N*128*4 B][bufB:N*128 f32]
// ---------------------------------------------------------------------------

__global__ void k_deg_count(const int* __restrict__ ei, int* __restrict__ deg, int E) {
    int e = blockIdx.x * blockDim.x + threadIdx.x;
    if (e < E) atomicAdd(&deg[ei[E + e]], 1);   // dst = ei[E+e]
}

__global__ void k_bsum(const int* __restrict__ deg, int* __restrict__ bsum, int n) {
    __shared__ int s[256];
    int t = threadIdx.x;
    int i = blockIdx.x * 256 + t;
    s[t] = (i < n) ? deg[i] : 0;
    __syncthreads();
    for (int off = 128; off > 0; off >>= 1) {
        if (t < off) s[t] += s[t + off];
        __syncthreads();
    }
    if (t == 0) bsum[blockIdx.x] = s[0];
}

__global__ void k_bscan(int* __restrict__ bsum, int* __restrict__ tot, int nb) {
    __shared__ int s[1024];
    int t = threadIdx.x;
    int v = (t < nb) ? bsum[t] : 0;
    s[t] = v;
    __syncthreads();
    for (int off = 1; off < 1024; off <<= 1) {
        int u = (t >= off) ? s[t - off] : 0;
        __syncthreads();
        s[t] += u;
        __syncthreads();
    }
    if (t < nb) bsum[t] = s[t] - v;
    if (t == nb - 1) tot[0] = s[t];
}

__global__ void k_rowptr(const int* __restrict__ deg, const int* __restrict__ bsum,
                         int* __restrict__ rowptr, int* __restrict__ cursor,
                         float* __restrict__ dinv, int n) {
    __shared__ int s[256];
    int t = threadIdx.x;
    int i = blockIdx.x * 256 + t;
    int v = (i < n) ? deg[i] : 0;
    s[t] = v;
    __syncthreads();
    for (int off = 1; off < 256; off <<= 1) {
        int u = (t >= off) ? s[t - off] : 0;
        __syncthreads();
        s[t] += u;
        __syncthreads();
    }
    if (i < n) {
        int ex = bsum[blockIdx.x] + s[t] - v;
        rowptr[i] = ex;
        cursor[i] = ex;
        dinv[i] = rsqrtf((float)(v + 1));   // +1 self-loop
    }
}

// XCD-partitioned scatter: block b handles dst in [(b&7)*n/8, ((b&7)+1)*n/8).
// csr is dst-ordered, so each partition's writes land in ONE contiguous span
// owned by one XCD's L2 -> lines written back ~once instead of ping-ponging.
__global__ __launch_bounds__(256) void k_fill(const int* __restrict__ ei,
                                              int* __restrict__ cursor,
                                              int* __restrict__ csr, int E, int n) {
    const int xcd = blockIdx.x & 7;
    const int e = (blockIdx.x >> 3) * 256 + threadIdx.x;
    if (e >= E) return;
    int d = ei[E + e];
    const int lo = (int)(((long long)xcd * n) >> 3);
    const int hi = (int)(((long long)(xcd + 1) * n) >> 3);
    if (d < lo || d >= hi) return;
    int s = ei[e];
    int pos = atomicAdd(&cursor[d], 1);
    csr[pos] = s;
}

__device__ __forceinline__ ushort_t f2bf_rne(float f) {
    uint_t u = __float_as_uint(f);
    u += 0x7fffu + ((u >> 16) & 1u);
    return (ushort_t)(u >> 16);
}
__device__ __forceinline__ float bflo(uint_t u) {
    return __uint_as_float(u << 16);
}
__device__ __forceinline__ float bfhi(uint_t u) {
    return __uint_as_float(u & 0xffff0000u);
}

// ---- Ybf16[N,128] = X[N,128] @ W[128,128].  BM=64, BK=32; 4x8 microtile.
__global__ __launch_bounds__(256) void k_gemm128(const float* __restrict__ X,
                                                 const float* __restrict__ W,
                                                 ushort_t* __restrict__ Y, int N) {
    __shared__ float sX[32][68];
    __shared__ float sW[32][128];
    const int tid = threadIdx.x;
    const int bm = blockIdx.x * 64;
    const int m0 = (tid >> 4) * 4;   // 0..60
    const int c4 = (tid & 15) * 4;   // 0..60
    const int xr = tid >> 3;
    const int xf = tid & 7;
    float acc[4][8] = {};
    for (int k0 = 0; k0 < 128; k0 += 32) {
        #pragma unroll
        for (int rr = 0; rr < 2; ++rr) {
            int row = bm + xr + rr * 32;
            int rc = min(row, N - 1);
            float4 v = *(const float4*)(X + (size_t)rc * 128 + k0 + xf * 4);
            int m = xr + rr * 32;
            sX[xf * 4 + 0][m] = v.x;
            sX[xf * 4 + 1][m] = v.y;
            sX[xf * 4 + 2][m] = v.z;
            sX[xf * 4 + 3][m] = v.w;
        }
        #pragma unroll
        for (int it = 0; it < 4; ++it) {
            int i = tid + it * 256;
            int wr = i >> 5;
            int wf = i & 31;
            *(float4*)(&sW[wr][wf * 4]) =
                *(const float4*)(W + (size_t)(k0 + wr) * 128 + wf * 4);
        }
        __syncthreads();
        #pragma unroll
        for (int kk = 0; kk < 32; ++kk) {
            float4 a  = *(const float4*)(&sX[kk][m0]);
            float4 b0 = *(const float4*)(&sW[kk][c4]);
            float4 b1 = *(const float4*)(&sW[kk][64 + c4]);
            float av[4] = {a.x, a.y, a.z, a.w};
            float bv[8] = {b0.x, b0.y, b0.z, b0.w, b1.x, b1.y, b1.z, b1.w};
            #pragma unroll
            for (int r = 0; r < 4; ++r)
                #pragma unroll
                for (int c = 0; c < 8; ++c)
                    acc[r][c] = fmaf(av[r], bv[c], acc[r][c]);
        }
        __syncthreads();
    }
    #pragma unroll
    for (int r = 0; r < 4; ++r) {
        int row = bm + m0 + r;
        if (row < N) {
            ushort4 o0 = {f2bf_rne(acc[r][0]), f2bf_rne(acc[r][1]),
                          f2bf_rne(acc[r][2]), f2bf_rne(acc[r][3])};
            ushort4 o1 = {f2bf_rne(acc[r][4]), f2bf_rne(acc[r][5]),
                          f2bf_rne(acc[r][6]), f2bf_rne(acc[r][7])};
            *(ushort4*)(Y + (size_t)row * 128 + c4)      = o0;
            *(ushort4*)(Y + (size_t)row * 128 + 64 + c4) = o1;
        }
    }
}

// ---- Ybf16[N,40 (stride 64)] = X[N,128] @ W[128,40].  BM=128, BK=32. ----
__global__ __launch_bounds__(256) void k_gemm40(const float* __restrict__ X,
                                                const float* __restrict__ W,
                                                ushort_t* __restrict__ Y, int N) {
    __shared__ float sX[32][132];
    __shared__ float sW[32][40];
    const int tid = threadIdx.x;
    const int bm = blockIdx.x * 128;
    const int m0 = (tid >> 3) * 4;
    const int n0 = (tid & 7) * 5;
    const int xf = tid & 7;
    float acc[4][5] = {};
    for (int k0 = 0; k0 < 128; k0 += 32) {
        #pragma unroll
        for (int it = 0; it < 4; ++it) {
            int i = tid + it * 256;
            int row = bm + (i >> 3);
            int rc = min(row, N - 1);
            float4 v = *(const float4*)(X + (size_t)rc * 128 + k0 + xf * 4);
            int m = i >> 3;
            sX[xf * 4 + 0][m] = v.x;
            sX[xf * 4 + 1][m] = v.y;
            sX[xf * 4 + 2][m] = v.z;
            sX[xf * 4 + 3][m] = v.w;
        }
        for (int i = tid; i < 320; i += 256) {
            int wr = i / 10;
            int wf = i - wr * 10;
            *(float4*)(&sW[wr][wf * 4]) =
                *(const float4*)(W + (size_t)(k0 + wr) * 40 + wf * 4);
        }
        __syncthreads();
        #pragma unroll
        for (int kk = 0; kk < 32; ++kk) {
            float4 a = *(const float4*)(&sX[kk][m0]);
            float av[4] = {a.x, a.y, a.z, a.w};
            #pragma unroll
            for (int c = 0; c < 5; ++c) {
                float b = sW[kk][n0 + c];
                #pragma unroll
                for (int r = 0; r < 4; ++r)
                    acc[r][c] = fmaf(av[r], b, acc[r][c]);
            }
        }
        __syncthreads();
    }
    #pragma unroll
    for (int r = 0; r < 4; ++r) {
        int row = bm + m0 + r;
        if (row < N) {
            #pragma unroll
            for (int c = 0; c < 5; ++c)
                Y[(size_t)row * 64 + n0 + c] = f2bf_rne(acc[r][c]);
        }
    }
}

// Sliced agg, F=128 bf16.  Half-wave handles (dst, 64-feature slice) = one
// aligned 128-B line per gather (ushort2/lane).  slice = (blockIdx&7)>>2.
template <bool RELU>
__global__ __launch_bounds__(256) void k_agg128(
        const ushort_t* __restrict__ XW, const int* __restrict__ rowptr,
        const int* __restrict__ csr, const float* __restrict__ dinv,
        const float* __restrict__ bias, float* __restrict__ out, int n) {
    const int lane = threadIdx.x & 31;
    const int sub  = threadIdx.x >> 5;              // 8 half-waves/block
    const int g = blockIdx.x;
    const int xcd = g & 7;
    const int slice = xcd >> 2;                     // 0 on XCD0-3, 1 on XCD4-7
    const int pair = (g >> 3) * 4 + (xcd & 3);      // dst-group index
    const int d = pair * 8 + sub;
    if (d >= n) return;
    const uint_t* xw = (const uint_t*)XW;           // ushort2 as uint; row stride 64
    const int fb = slice * 32 + lane;               // uint index within row
    float dv = dinv[d];
    float w0 = dv * dv;
    uint_t sq = xw[(size_t)d * 64 + fb];
    float2 a;
    a.x = w0 * bflo(sq);
    a.y = w0 * bfhi(sq);
    int j = rowptr[d], end = rowptr[d + 1];
    for (; j + 8 <= end; j += 8) {
        int s0 = csr[j + 0], s1 = csr[j + 1], s2 = csr[j + 2], s3 = csr[j + 3];
        int s4 = csr[j + 4], s5 = csr[j + 5], s6 = csr[j + 6], s7 = csr[j + 7];
        float w0e = dinv[s0] * dv, w1e = dinv[s1] * dv;
        float w2e = dinv[s2] * dv, w3e = dinv[s3] * dv;
        float w4e = dinv[s4] * dv, w5e = dinv[s5] * dv;
        float w6e = dinv[s6] * dv, w7e = dinv[s7] * dv;
        uint_t u0 = xw[(size_t)s0 * 64 + fb];
        uint_t u1 = xw[(size_t)s1 * 64 + fb];
        uint_t u2 = xw[(size_t)s2 * 64 + fb];
        uint_t u3 = xw[(size_t)s3 * 64 + fb];
        uint_t u4 = xw[(size_t)s4 * 64 + fb];
        uint_t u5 = xw[(size_t)s5 * 64 + fb];
        uint_t u6 = xw[(size_t)s6 * 64 + fb];
        uint_t u7 = xw[(size_t)s7 * 64 + fb];
        a.x = fmaf(w0e, bflo(u0), a.x); a.y = fmaf(w0e, bfhi(u0), a.y);
        a.x = fmaf(w1e, bflo(u1), a.x); a.y = fmaf(w1e, bfhi(u1), a.y);
        a.x = fmaf(w2e, bflo(u2), a.x); a.y = fmaf(w2e, bfhi(u2), a.y);
        a.x = fmaf(w3e, bflo(u3), a.x); a.y = fmaf(w3e, bfhi(u3), a.y);
        a.x = fmaf(w4e, bflo(u4), a.x); a.y = fmaf(w4e, bfhi(u4), a.y);
        a.x = fmaf(w5e, bflo(u5), a.x); a.y = fmaf(w5e, bfhi(u5), a.y);
        a.x = fmaf(w6e, bflo(u6), a.x); a.y = fmaf(w6e, bfhi(u6), a.y);
        a.x = fmaf(w7e, bflo(u7), a.x); a.y = fmaf(w7e, bfhi(u7), a.y);
    }
    for (; j < end; ++j) {
        int s = csr[j];
        float we = dinv[s] * dv;
        uint_t u = xw[(size_t)s * 64 + fb];
        a.x = fmaf(we, bflo(u), a.x);
        a.y = fmaf(we, bfhi(u), a.y);
    }
    float2 b = ((const float2*)bias)[fb];
    a.x += b.x; a.y += b.y;
    if (RELU) {
        a.x = fmaxf(a.x, 0.f);
        a.y = fmaxf(a.y, 0.f);
    }
    ((float2*)out)[(size_t)d * 64 + fb] = a;
}

// Half-wave per dst, F=40 bf16 rows padded to stride 64 (one 128-B line).
__global__ __launch_bounds__(256) void k_agg40(
        const ushort_t* __restrict__ XW, const int* __restrict__ rowptr,
        const int* __restrict__ csr, const float* __restrict__ dinv,
        const float* __restrict__ bias, float* __restrict__ out, int n) {
    const int lane = threadIdx.x & 31;
    const int sub  = threadIdx.x >> 5;
    const int d = blockIdx.x * 8 + sub;
    if (d >= n || lane >= 20) return;
    const uint_t* xw = (const uint_t*)XW;       // row stride 32 uints
    float dv = dinv[d];
    float w0 = dv * dv;
    uint_t sq = xw[(size_t)d * 32 + lane];
    float2 a;
    a.x = w0 * bflo(sq);
    a.y = w0 * bfhi(sq);
    int j = rowptr[d], end = rowptr[d + 1];
    for (; j + 4 <= end; j += 4) {
        int s0 = csr[j + 0], s1 = csr[j + 1], s2 = csr[j + 2], s3 = csr[j + 3];
        float w0e = dinv[s0] * dv, w1e = dinv[s1] * dv;
        float w2e = dinv[s2] * dv, w3e = dinv[s3] * dv;
        uint_t u0 = xw[(size_t)s0 * 32 + lane];
        uint_t u1 = xw[(size_t)s1 * 32 + lane];
        uint_t u2 = xw[(size_t)s2 * 32 + lane];
        uint_t u3 = xw[(size_t)s3 * 32 + lane];
        a.x = fmaf(w0e, bflo(u0), a.x); a.y = fmaf(w0e, bfhi(u0), a.y);
        a.x = fmaf(w1e, bflo(u1), a.x); a.y = fmaf(w1e, bfhi(u1), a.y);
        a.x = fmaf(w2e, bflo(u2), a.x); a.y = fmaf(w2e, bfhi(u2), a.y);
        a.x = fmaf(w3e, bflo(u3), a.x); a.y = fmaf(w3e, bfhi(u3), a.y);
    }
    for (; j < end; ++j) {
        int s = csr[j];
        float we = dinv[s] * dv;
        uint_t u = xw[(size_t)s * 32 + lane];
        a.x = fmaf(we, bflo(u), a.x);
        a.y = fmaf(we, bfhi(u), a.y);
    }
    float2 b = ((const float2*)bias)[lane];
    a.x += b.x; a.y += b.y;
    ((float2*)out)[(size_t)d * 20 + lane] = a;
}

static inline int cdiv(long long a, int b) { return (int)((a + b - 1) / b); }

extern "C" void kernel_launch(void* const* d_in, const int* in_sizes, int n_in,
                              void* d_out, int out_size, void* d_ws, size_t ws_size,
                              hipStream_t stream) {
    const float* x  = (const float*)d_in[0];
    const int*   ei = (const int*)d_in[1];
    const float* W1 = (const float*)d_in[2];
    const float* b1 = (const float*)d_in[3];
    const float* W2 = (const float*)d_in[4];
    const float* b2 = (const float*)d_in[5];
    const float* W3 = (const float*)d_in[6];
    const float* b3 = (const float*)d_in[7];
    float* out = (float*)d_out;

    const int N = in_sizes[0] / 128;   // 50000
    const int E = in_sizes[1] / 2;     // 800000

    char* ws = (char*)d_ws;
    int*   deg    = (int*)ws;                 ws += (size_t)N * 4;
    int*   rowptr = (int*)ws;                 ws += (size_t)(N + 1) * 4;
    int*   cursor = (int*)ws;                 ws += (size_t)N * 4;
    float* dinv   = (float*)ws;               ws += (size_t)N * 4;
    int*   bsum   = (int*)ws;                 ws += (size_t)1024 * 4;
    ws = (char*)(((uintptr_t)ws + 127) & ~(uintptr_t)127);
    int*   csr    = (int*)ws;                 ws += (size_t)E * 4;       // 3.2 MB, 128-B aligned
    char*  bufA   = ws;                       ws += (size_t)N * 128 * 4; // bf16 XW / bf16 XW40
    float* bufB   = (float*)ws;

    const int BT = 256;
    const int nb = cdiv(N, 256);
    const int ndg = cdiv(N, 8);                       // dst-groups of 8
    const int agg128Grid = cdiv(ndg, 4) * 8;          // 4 dst-groups x 2 slices per 8 blocks

    // CSR build (per call; no state survives between calls)
    hipMemsetAsync(deg, 0, (size_t)N * 4, stream);
    k_deg_count<<<cdiv(E, BT), BT, 0, stream>>>(ei, deg, E);
    k_bsum<<<nb, 256, 0, stream>>>(deg, bsum, N);
    k_bscan<<<1, 1024, 0, stream>>>(bsum, rowptr + N, nb);
    k_rowptr<<<nb, 256, 0, stream>>>(deg, bsum, rowptr, cursor, dinv, N);
    k_fill<<<cdiv(E, BT) * 8, 256, 0, stream>>>(ei, cursor, csr, E, N);

    // layer 1
    k_gemm128<<<cdiv(N, 64), 256, 0, stream>>>(x, W1, (ushort_t*)bufA, N);
    k_agg128<true><<<agg128Grid, 256, 0, stream>>>((const ushort_t*)bufA, rowptr, csr, dinv, b1, bufB, N);
    // layer 2
    k_gemm128<<<cdiv(N, 64), 256, 0, stream>>>(bufB, W2, (ushort_t*)bufA, N);
    k_agg128<true><<<agg128Grid, 256, 0, stream>>>((const ushort_t*)bufA, rowptr, csr, dinv, b2, bufB, N);
    // layer 3 (bf16 staged, rows padded to one 128-B line)
    k_gemm40<<<cdiv(N, 128), 256, 0, stream>>>(bufB, W3, (ushort_t*)bufA, N);
    k_agg40<<<cdiv(N, 8), 256, 0, stream>>>((const ushort_t*)bufA, rowptr, csr, dinv, b3, out, N);
}

// Round 13
// 327.534 us; speedup vs baseline: 1.0813x; 1.0456x over previous
//
#include <hip/hip_runtime.h>

typedef unsigned short ushort_t;
typedef unsigned int uint_t;

// ---------------------------------------------------------------------------
// GCN 3-layer forward.  N=50000, E=800000, D=H=128, C=40.
// Round 13: uniform full-wave agg128.  R10/R12 showed agg128 time is
// insensitive to traffic (93 MB and 62 MB both ~47 us) -> issue/divergence
// bound, caused by 2 dsts per wave (divergent edge loop, unscalarizable
// csr/dinv loads).  Now ONE wave per dst: lane i owns uint i of the 256-B
// bf16 row; d/j/csr[s]/dinv[s] are wave-uniform -> scalar loads (s_load),
// SGPR weight operand in FMAs, zero divergence.  2-way XCD slice dropped
// (bytes proven non-binding).  fill XCD-partition, 4B csr, bf16 staging,
// padded agg40 kept.  FMA order per (dst,feature) unchanged.
// ws layout: [deg:N int][rowptr:N+1 int][cursor:N int][dinv:N f32][bsum:1024 int]
//            [csr:E int (src)][bufA:N*128*4 B][bufB:N*128 f32]
// ---------------------------------------------------------------------------

__global__ void k_deg_count(const int* __restrict__ ei, int* __restrict__ deg, int E) {
    int e = blockIdx.x * blockDim.x + threadIdx.x;
    if (e < E) atomicAdd(&deg[ei[E + e]], 1);   // dst = ei[E+e]
}

__global__ void k_bsum(const int* __restrict__ deg, int* __restrict__ bsum, int n) {
    __shared__ int s[256];
    int t = threadIdx.x;
    int i = blockIdx.x * 256 + t;
    s[t] = (i < n) ? deg[i] : 0;
    __syncthreads();
    for (int off = 128; off > 0; off >>= 1) {
        if (t < off) s[t] += s[t + off];
        __syncthreads();
    }
    if (t == 0) bsum[blockIdx.x] = s[0];
}

__global__ void k_bscan(int* __restrict__ bsum, int* __restrict__ tot, int nb) {
    __shared__ int s[1024];
    int t = threadIdx.x;
    int v = (t < nb) ? bsum[t] : 0;
    s[t] = v;
    __syncthreads();
    for (int off = 1; off < 1024; off <<= 1) {
        int u = (t >= off) ? s[t - off] : 0;
        __syncthreads();
        s[t] += u;
        __syncthreads();
    }
    if (t < nb) bsum[t] = s[t] - v;
    if (t == nb - 1) tot[0] = s[t];
}

__global__ void k_rowptr(const int* __restrict__ deg, const int* __restrict__ bsum,
                         int* __restrict__ rowptr, int* __restrict__ cursor,
                         float* __restrict__ dinv, int n) {
    __shared__ int s[256];
    int t = threadIdx.x;
    int i = blockIdx.x * 256 + t;
    int v = (i < n) ? deg[i] : 0;
    s[t] = v;
    __syncthreads();
    for (int off = 1; off < 256; off <<= 1) {
        int u = (t >= off) ? s[t - off] : 0;
        __syncthreads();
        s[t] += u;
        __syncthreads();
    }
    if (i < n) {
        int ex = bsum[blockIdx.x] + s[t] - v;
        rowptr[i] = ex;
        cursor[i] = ex;
        dinv[i] = rsqrtf((float)(v + 1));   // +1 self-loop
    }
}

// XCD-partitioned scatter (R12): block b serves dst in [(b&7)*n/8, ...).
__global__ __launch_bounds__(256) void k_fill(const int* __restrict__ ei,
                                              int* __restrict__ cursor,
                                              int* __restrict__ csr, int E, int n) {
    const int xcd = blockIdx.x & 7;
    const int e = (blockIdx.x >> 3) * 256 + threadIdx.x;
    if (e >= E) return;
    int d = ei[E + e];
    const int lo = (int)(((long long)xcd * n) >> 3);
    const int hi = (int)(((long long)(xcd + 1) * n) >> 3);
    if (d < lo || d >= hi) return;
    int s = ei[e];
    int pos = atomicAdd(&cursor[d], 1);
    csr[pos] = s;
}

__device__ __forceinline__ ushort_t f2bf_rne(float f) {
    uint_t u = __float_as_uint(f);
    u += 0x7fffu + ((u >> 16) & 1u);
    return (ushort_t)(u >> 16);
}
__device__ __forceinline__ float bflo(uint_t u) {
    return __uint_as_float(u << 16);
}
__device__ __forceinline__ float bfhi(uint_t u) {
    return __uint_as_float(u & 0xffff0000u);
}

// ---- Ybf16[N,128] = X[N,128] @ W[128,128].  BM=64, BK=32; 4x8 microtile.
__global__ __launch_bounds__(256) void k_gemm128(const float* __restrict__ X,
                                                 const float* __restrict__ W,
                                                 ushort_t* __restrict__ Y, int N) {
    __shared__ float sX[32][68];
    __shared__ float sW[32][128];
    const int tid = threadIdx.x;
    const int bm = blockIdx.x * 64;
    const int m0 = (tid >> 4) * 4;   // 0..60
    const int c4 = (tid & 15) * 4;   // 0..60
    const int xr = tid >> 3;
    const int xf = tid & 7;
    float acc[4][8] = {};
    for (int k0 = 0; k0 < 128; k0 += 32) {
        #pragma unroll
        for (int rr = 0; rr < 2; ++rr) {
            int row = bm + xr + rr * 32;
            int rc = min(row, N - 1);
            float4 v = *(const float4*)(X + (size_t)rc * 128 + k0 + xf * 4);
            int m = xr + rr * 32;
            sX[xf * 4 + 0][m] = v.x;
            sX[xf * 4 + 1][m] = v.y;
            sX[xf * 4 + 2][m] = v.z;
            sX[xf * 4 + 3][m] = v.w;
        }
        #pragma unroll
        for (int it = 0; it < 4; ++it) {
            int i = tid + it * 256;
            int wr = i >> 5;
            int wf = i & 31;
            *(float4*)(&sW[wr][wf * 4]) =
                *(const float4*)(W + (size_t)(k0 + wr) * 128 + wf * 4);
        }
        __syncthreads();
        #pragma unroll
        for (int kk = 0; kk < 32; ++kk) {
            float4 a  = *(const float4*)(&sX[kk][m0]);
            float4 b0 = *(const float4*)(&sW[kk][c4]);
            float4 b1 = *(const float4*)(&sW[kk][64 + c4]);
            float av[4] = {a.x, a.y, a.z, a.w};
            float bv[8] = {b0.x, b0.y, b0.z, b0.w, b1.x, b1.y, b1.z, b1.w};
            #pragma unroll
            for (int r = 0; r < 4; ++r)
                #pragma unroll
                for (int c = 0; c < 8; ++c)
                    acc[r][c] = fmaf(av[r], bv[c], acc[r][c]);
        }
        __syncthreads();
    }
    #pragma unroll
    for (int r = 0; r < 4; ++r) {
        int row = bm + m0 + r;
        if (row < N) {
            ushort4 o0 = {f2bf_rne(acc[r][0]), f2bf_rne(acc[r][1]),
                          f2bf_rne(acc[r][2]), f2bf_rne(acc[r][3])};
            ushort4 o1 = {f2bf_rne(acc[r][4]), f2bf_rne(acc[r][5]),
                          f2bf_rne(acc[r][6]), f2bf_rne(acc[r][7])};
            *(ushort4*)(Y + (size_t)row * 128 + c4)      = o0;
            *(ushort4*)(Y + (size_t)row * 128 + 64 + c4) = o1;
        }
    }
}

// ---- Ybf16[N,40 (stride 64)] = X[N,128] @ W[128,40].  BM=128, BK=32. ----
__global__ __launch_bounds__(256) void k_gemm40(const float* __restrict__ X,
                                                const float* __restrict__ W,
                                                ushort_t* __restrict__ Y, int N) {
    __shared__ float sX[32][132];
    __shared__ float sW[32][40];
    const int tid = threadIdx.x;
    const int bm = blockIdx.x * 128;
    const int m0 = (tid >> 3) * 4;
    const int n0 = (tid & 7) * 5;
    const int xf = tid & 7;
    float acc[4][5] = {};
    for (int k0 = 0; k0 < 128; k0 += 32) {
        #pragma unroll
        for (int it = 0; it < 4; ++it) {
            int i = tid + it * 256;
            int row = bm + (i >> 3);
            int rc = min(row, N - 1);
            float4 v = *(const float4*)(X + (size_t)rc * 128 + k0 + xf * 4);
            int m = i >> 3;
            sX[xf * 4 + 0][m] = v.x;
            sX[xf * 4 + 1][m] = v.y;
            sX[xf * 4 + 2][m] = v.z;
            sX[xf * 4 + 3][m] = v.w;
        }
        for (int i = tid; i < 320; i += 256) {
            int wr = i / 10;
            int wf = i - wr * 10;
            *(float4*)(&sW[wr][wf * 4]) =
                *(const float4*)(W + (size_t)(k0 + wr) * 40 + wf * 4);
        }
        __syncthreads();
        #pragma unroll
        for (int kk = 0; kk < 32; ++kk) {
            float4 a = *(const float4*)(&sX[kk][m0]);
            float av[4] = {a.x, a.y, a.z, a.w};
            #pragma unroll
            for (int c = 0; c < 5; ++c) {
                float b = sW[kk][n0 + c];
                #pragma unroll
                for (int r = 0; r < 4; ++r)
                    acc[r][c] = fmaf(av[r], b, acc[r][c]);
            }
        }
        __syncthreads();
    }
    #pragma unroll
    for (int r = 0; r < 4; ++r) {
        int row = bm + m0 + r;
        if (row < N) {
            #pragma unroll
            for (int c = 0; c < 5; ++c)
                Y[(size_t)row * 64 + n0 + c] = f2bf_rne(acc[r][c]);
        }
    }
}

// Uniform full-wave agg, F=128 bf16.  One 64-lane wave per dst; lane i owns
// uint i (2 features) of the 256-B row.  d/j/csr/dinv are wave-uniform
// (readfirstlane-forced) -> scalar loads, SGPR weight in FMA, no divergence.
template <bool RELU>
__global__ __launch_bounds__(256) void k_agg128(
        const ushort_t* __restrict__ XW, const int* __restrict__ rowptr,
        const int* __restrict__ csr, const float* __restrict__ dinv,
        const float* __restrict__ bias, float* __restrict__ out, int n) {
    const int lane = threadIdx.x & 63;
    const int wv = __builtin_amdgcn_readfirstlane(threadIdx.x >> 6);  // 0..3, SGPR
    const int d = blockIdx.x * 4 + wv;                                // uniform
    if (d >= n) return;
    const uint_t* xw = (const uint_t*)XW;           // row stride 64 uints (256 B)
    float dv = dinv[d];
    float w0 = dv * dv;
    uint_t sq = xw[(size_t)d * 64 + lane];
    float2 a;
    a.x = w0 * bflo(sq);
    a.y = w0 * bfhi(sq);
    int j = rowptr[d], end = rowptr[d + 1];         // uniform
    for (; j + 8 <= end; j += 8) {
        int s0 = csr[j + 0], s1 = csr[j + 1], s2 = csr[j + 2], s3 = csr[j + 3];
        int s4 = csr[j + 4], s5 = csr[j + 5], s6 = csr[j + 6], s7 = csr[j + 7];
        float w0e = dinv[s0] * dv, w1e = dinv[s1] * dv;
        float w2e = dinv[s2] * dv, w3e = dinv[s3] * dv;
        float w4e = dinv[s4] * dv, w5e = dinv[s5] * dv;
        float w6e = dinv[s6] * dv, w7e = dinv[s7] * dv;
        uint_t u0 = xw[(size_t)s0 * 64 + lane];
        uint_t u1 = xw[(size_t)s1 * 64 + lane];
        uint_t u2 = xw[(size_t)s2 * 64 + lane];
        uint_t u3 = xw[(size_t)s3 * 64 + lane];
        uint_t u4 = xw[(size_t)s4 * 64 + lane];
        uint_t u5 = xw[(size_t)s5 * 64 + lane];
        uint_t u6 = xw[(size_t)s6 * 64 + lane];
        uint_t u7 = xw[(size_t)s7 * 64 + lane];
        a.x = fmaf(w0e, bflo(u0), a.x); a.y = fmaf(w0e, bfhi(u0), a.y);
        a.x = fmaf(w1e, bflo(u1), a.x); a.y = fmaf(w1e, bfhi(u1), a.y);
        a.x = fmaf(w2e, bflo(u2), a.x); a.y = fmaf(w2e, bfhi(u2), a.y);
        a.x = fmaf(w3e, bflo(u3), a.x); a.y = fmaf(w3e, bfhi(u3), a.y);
        a.x = fmaf(w4e, bflo(u4), a.x); a.y = fmaf(w4e, bfhi(u4), a.y);
        a.x = fmaf(w5e, bflo(u5), a.x); a.y = fmaf(w5e, bfhi(u5), a.y);
        a.x = fmaf(w6e, bflo(u6), a.x); a.y = fmaf(w6e, bfhi(u6), a.y);
        a.x = fmaf(w7e, bflo(u7), a.x); a.y = fmaf(w7e, bfhi(u7), a.y);
    }
    for (; j < end; ++j) {
        int s = csr[j];
        float we = dinv[s] * dv;
        uint_t u = xw[(size_t)s * 64 + lane];
        a.x = fmaf(we, bflo(u), a.x);
        a.y = fmaf(we, bfhi(u), a.y);
    }
    float2 b = ((const float2*)bias)[lane];
    a.x += b.x; a.y += b.y;
    if (RELU) {
        a.x = fmaxf(a.x, 0.f);
        a.y = fmaxf(a.y, 0.f);
    }
    ((float2*)out)[(size_t)d * 64 + lane] = a;
}

// Half-wave per dst, F=40 bf16 rows padded to stride 64 (one 128-B line).
__global__ __launch_bounds__(256) void k_agg40(
        const ushort_t* __restrict__ XW, const int* __restrict__ rowptr,
        const int* __restrict__ csr, const float* __restrict__ dinv,
        const float* __restrict__ bias, float* __restrict__ out, int n) {
    const int lane = threadIdx.x & 31;
    const int sub  = threadIdx.x >> 5;
    const int d = blockIdx.x * 8 + sub;
    if (d >= n || lane >= 20) return;
    const uint_t* xw = (const uint_t*)XW;       // row stride 32 uints
    float dv = dinv[d];
    float w0 = dv * dv;
    uint_t sq = xw[(size_t)d * 32 + lane];
    float2 a;
    a.x = w0 * bflo(sq);
    a.y = w0 * bfhi(sq);
    int j = rowptr[d], end = rowptr[d + 1];
    for (; j + 4 <= end; j += 4) {
        int s0 = csr[j + 0], s1 = csr[j + 1], s2 = csr[j + 2], s3 = csr[j + 3];
        float w0e = dinv[s0] * dv, w1e = dinv[s1] * dv;
        float w2e = dinv[s2] * dv, w3e = dinv[s3] * dv;
        uint_t u0 = xw[(size_t)s0 * 32 + lane];
        uint_t u1 = xw[(size_t)s1 * 32 + lane];
        uint_t u2 = xw[(size_t)s2 * 32 + lane];
        uint_t u3 = xw[(size_t)s3 * 32 + lane];
        a.x = fmaf(w0e, bflo(u0), a.x); a.y = fmaf(w0e, bfhi(u0), a.y);
        a.x = fmaf(w1e, bflo(u1), a.x); a.y = fmaf(w1e, bfhi(u1), a.y);
        a.x = fmaf(w2e, bflo(u2), a.x); a.y = fmaf(w2e, bfhi(u2), a.y);
        a.x = fmaf(w3e, bflo(u3), a.x); a.y = fmaf(w3e, bfhi(u3), a.y);
    }
    for (; j < end; ++j) {
        int s = csr[j];
        float we = dinv[s] * dv;
        uint_t u = xw[(size_t)s * 32 + lane];
        a.x = fmaf(we, bflo(u), a.x);
        a.y = fmaf(we, bfhi(u), a.y);
    }
    float2 b = ((const float2*)bias)[lane];
    a.x += b.x; a.y += b.y;
    ((float2*)out)[(size_t)d * 20 + lane] = a;
}

static inline int cdiv(long long a, int b) { return (int)((a + b - 1) / b); }

extern "C" void kernel_launch(void* const* d_in, const int* in_sizes, int n_in,
                              void* d_out, int out_size, void* d_ws, size_t ws_size,
                              hipStream_t stream) {
    const float* x  = (const float*)d_in[0];
    const int*   ei = (const int*)d_in[1];
    const float* W1 = (const float*)d_in[2];
    const float* b1 = (const float*)d_in[3];
    const float* W2 = (const float*)d_in[4];
    const float* b2 = (const float*)d_in[5];
    const float* W3 = (const float*)d_in[6];
    const float* b3 = (const float*)d_in[7];
    float* out = (float*)d_out;

    const int N = in_sizes[0] / 128;   // 50000
    const int E = in_sizes[1] / 2;     // 800000

    char* ws = (char*)d_ws;
    int*   deg    = (int*)ws;                 ws += (size_t)N * 4;
    int*   rowptr = (int*)ws;                 ws += (size_t)(N + 1) * 4;
    int*   cursor = (int*)ws;                 ws += (size_t)N * 4;
    float* dinv   = (float*)ws;               ws += (size_t)N * 4;
    int*   bsum   = (int*)ws;                 ws += (size_t)1024 * 4;
    ws = (char*)(((uintptr_t)ws + 127) & ~(uintptr_t)127);
    int*   csr    = (int*)ws;                 ws += (size_t)E * 4;       // 3.2 MB, 128-B aligned
    char*  bufA   = ws;                       ws += (size_t)N * 128 * 4; // bf16 XW / bf16 XW40
    float* bufB   = (float*)ws;

    const int BT = 256;
    const int nb = cdiv(N, 256);

    // CSR build (per call; no state survives between calls)
    hipMemsetAsync(deg, 0, (size_t)N * 4, stream);
    k_deg_count<<<cdiv(E, BT), BT, 0, stream>>>(ei, deg, E);
    k_bsum<<<nb, 256, 0, stream>>>(deg, bsum, N);
    k_bscan<<<1, 1024, 0, stream>>>(bsum, rowptr + N, nb);
    k_rowptr<<<nb, 256, 0, stream>>>(deg, bsum, rowptr, cursor, dinv, N);
    k_fill<<<cdiv(E, BT) * 8, 256, 0, stream>>>(ei, cursor, csr, E, N);

    // layer 1
    k_gemm128<<<cdiv(N, 64), 256, 0, stream>>>(x, W1, (ushort_t*)bufA, N);
    k_agg128<true><<<cdiv(N, 4), 256, 0, stream>>>((const ushort_t*)bufA, rowptr, csr, dinv, b1, bufB, N);
    // layer 2
    k_gemm128<<<cdiv(N, 64), 256, 0, stream>>>(bufB, W2, (ushort_t*)bufA, N);
    k_agg128<true><<<cdiv(N, 4), 256, 0, stream>>>((const ushort_t*)bufA, rowptr, csr, dinv, b2, bufB, N);
    // layer 3 (bf16 staged, rows padded to one 128-B line)
    k_gemm40<<<cdiv(N, 128), 256, 0, stream>>>(bufB, W3, (ushort_t*)bufA, N);
    k_agg40<<<cdiv(N, 8), 256, 0, stream>>>((const ushort_t*)bufA, rowptr, csr, dinv, b3, out, N);
}

// Round 14
// 321.781 us; speedup vs baseline: 1.1006x; 1.0179x over previous
//
#include <hip/hip_runtime.h>

typedef unsigned short ushort_t;
typedef unsigned int uint_t;

// ---------------------------------------------------------------------------
// GCN 3-layer forward.  N=50000, E=800000, D=H=128, C=40.
// Round 14: (1) csr back to 8-B (src, w) entries — kills the dependent
// dinv[s] scalar-load chain in the uniform-wave agg loops (csr batch is one
// independent s_load group).  Weight computed in k_fill with the identical
// fmul -> bitwise-identical results.  R12's XCD-partitioned fill keeps the
// scatter cheap.  (2) gemm128: 128x128 tile, 8x8 microtile -> 64 FMAs per
// 64 B LDS (1.5x better ratio), reads <=2-way bank-aliased.
// ws layout: [deg:N int][rowptr:N+1 int][cursor:N int][dinv:N f32][bsum:1024 int]
//            [csr:E int2][bufA:N*128*4 B][bufB:N*128 f32]
// ---------------------------------------------------------------------------

__global__ void k_deg_count(const int* __restrict__ ei, int* __restrict__ deg, int E) {
    int e = blockIdx.x * blockDim.x + threadIdx.x;
    if (e < E) atomicAdd(&deg[ei[E + e]], 1);   // dst = ei[E+e]
}

__global__ void k_bsum(const int* __restrict__ deg, int* __restrict__ bsum, int n) {
    __shared__ int s[256];
    int t = threadIdx.x;
    int i = blockIdx.x * 256 + t;
    s[t] = (i < n) ? deg[i] : 0;
    __syncthreads();
    for (int off = 128; off > 0; off >>= 1) {
        if (t < off) s[t] += s[t + off];
        __syncthreads();
    }
    if (t == 0) bsum[blockIdx.x] = s[0];
}

__global__ void k_bscan(int* __restrict__ bsum, int* __restrict__ tot, int nb) {
    __shared__ int s[1024];
    int t = threadIdx.x;
    int v = (t < nb) ? bsum[t] : 0;
    s[t] = v;
    __syncthreads();
    for (int off = 1; off < 1024; off <<= 1) {
        int u = (t >= off) ? s[t - off] : 0;
        __syncthreads();
        s[t] += u;
        __syncthreads();
    }
    if (t < nb) bsum[t] = s[t] - v;
    if (t == nb - 1) tot[0] = s[t];
}

__global__ void k_rowptr(const int* __restrict__ deg, const int* __restrict__ bsum,
                         int* __restrict__ rowptr, int* __restrict__ cursor,
                         float* __restrict__ dinv, int n) {
    __shared__ int s[256];
    int t = threadIdx.x;
    int i = blockIdx.x * 256 + t;
    int v = (i < n) ? deg[i] : 0;
    s[t] = v;
    __syncthreads();
    for (int off = 1; off < 256; off <<= 1) {
        int u = (t >= off) ? s[t - off] : 0;
        __syncthreads();
        s[t] += u;
        __syncthreads();
    }
    if (i < n) {
        int ex = bsum[blockIdx.x] + s[t] - v;
        rowptr[i] = ex;
        cursor[i] = ex;
        dinv[i] = rsqrtf((float)(v + 1));   // +1 self-loop
    }
}

// XCD-partitioned scatter (R12): block b serves dst in [(b&7)*n/8, ...).
// Entry = {src, bits(dinv[src]*dinv[dst])}.
__global__ __launch_bounds__(256) void k_fill(const int* __restrict__ ei,
                                              int* __restrict__ cursor,
                                              const float* __restrict__ dinv,
                                              int2* __restrict__ csr, int E, int n) {
    const int xcd = blockIdx.x & 7;
    const int e = (blockIdx.x >> 3) * 256 + threadIdx.x;
    if (e >= E) return;
    int d = ei[E + e];
    const int lo = (int)(((long long)xcd * n) >> 3);
    const int hi = (int)(((long long)(xcd + 1) * n) >> 3);
    if (d < lo || d >= hi) return;
    int s = ei[e];
    int pos = atomicAdd(&cursor[d], 1);
    int2 p;
    p.x = s;
    p.y = __float_as_int(dinv[s] * dinv[d]);
    csr[pos] = p;
}

__device__ __forceinline__ ushort_t f2bf_rne(float f) {
    uint_t u = __float_as_uint(f);
    u += 0x7fffu + ((u >> 16) & 1u);
    return (ushort_t)(u >> 16);
}
__device__ __forceinline__ float bflo(uint_t u) {
    return __uint_as_float(u << 16);
}
__device__ __forceinline__ float bfhi(uint_t u) {
    return __uint_as_float(u & 0xffff0000u);
}

// ---- Ybf16[N,128] = X[N,128] @ W[128,128].  BM=128, BK=32; 8x8 microtile.
// sX read: 4 distinct addresses/wave (16-lane broadcast) -> conflict-free.
// sW read: stride-4 across 16 groups -> 2-way aliasing (free).
__global__ __launch_bounds__(256) void k_gemm128(const float* __restrict__ X,
                                                 const float* __restrict__ W,
                                                 ushort_t* __restrict__ Y, int N) {
    __shared__ float sX[32][132];   // [k][m]
    __shared__ float sW[32][128];   // [k][n]
    const int tid = threadIdx.x;
    const int bm = blockIdx.x * 128;
    const int m0 = (tid >> 4) * 8;   // 0..120
    const int c4 = (tid & 15) * 4;   // 0..60 ; cols {c4..c4+3} u {64+c4..67+c4}
    const int xf = tid & 7;
    float acc[8][8] = {};
    for (int k0 = 0; k0 < 128; k0 += 32) {
        #pragma unroll
        for (int it = 0; it < 4; ++it) {
            int i = tid + it * 256;          // 0..1023: 8 threads/row, 128 rows
            int row = bm + (i >> 3);
            int rc = min(row, N - 1);
            float4 v = *(const float4*)(X + (size_t)rc * 128 + k0 + xf * 4);
            int m = i >> 3;
            sX[xf * 4 + 0][m] = v.x;
            sX[xf * 4 + 1][m] = v.y;
            sX[xf * 4 + 2][m] = v.z;
            sX[xf * 4 + 3][m] = v.w;
        }
        #pragma unroll
        for (int it = 0; it < 4; ++it) {
            int i = tid + it * 256;
            int wr = i >> 5;
            int wf = i & 31;
            *(float4*)(&sW[wr][wf * 4]) =
                *(const float4*)(W + (size_t)(k0 + wr) * 128 + wf * 4);
        }
        __syncthreads();
        #pragma unroll
        for (int kk = 0; kk < 32; ++kk) {
            float4 a0 = *(const float4*)(&sX[kk][m0]);
            float4 a1 = *(const float4*)(&sX[kk][m0 + 4]);
            float4 b0 = *(const float4*)(&sW[kk][c4]);
            float4 b1 = *(const float4*)(&sW[kk][64 + c4]);
            float av[8] = {a0.x, a0.y, a0.z, a0.w, a1.x, a1.y, a1.z, a1.w};
            float bv[8] = {b0.x, b0.y, b0.z, b0.w, b1.x, b1.y, b1.z, b1.w};
            #pragma unroll
            for (int r = 0; r < 8; ++r)
                #pragma unroll
                for (int c = 0; c < 8; ++c)
                    acc[r][c] = fmaf(av[r], bv[c], acc[r][c]);
        }
        __syncthreads();
    }
    #pragma unroll
    for (int r = 0; r < 8; ++r) {
        int row = bm + m0 + r;
        if (row < N) {
            ushort4 o0 = {f2bf_rne(acc[r][0]), f2bf_rne(acc[r][1]),
                          f2bf_rne(acc[r][2]), f2bf_rne(acc[r][3])};
            ushort4 o1 = {f2bf_rne(acc[r][4]), f2bf_rne(acc[r][5]),
                          f2bf_rne(acc[r][6]), f2bf_rne(acc[r][7])};
            *(ushort4*)(Y + (size_t)row * 128 + c4)      = o0;
            *(ushort4*)(Y + (size_t)row * 128 + 64 + c4) = o1;
        }
    }
}

// ---- Ybf16[N,40 (stride 64)] = X[N,128] @ W[128,40].  BM=128, BK=32. ----
__global__ __launch_bounds__(256) void k_gemm40(const float* __restrict__ X,
                                                const float* __restrict__ W,
                                                ushort_t* __restrict__ Y, int N) {
    __shared__ float sX[32][132];
    __shared__ float sW[32][40];
    const int tid = threadIdx.x;
    const int bm = blockIdx.x * 128;
    const int m0 = (tid >> 3) * 4;
    const int n0 = (tid & 7) * 5;
    const int xf = tid & 7;
    float acc[4][5] = {};
    for (int k0 = 0; k0 < 128; k0 += 32) {
        #pragma unroll
        for (int it = 0; it < 4; ++it) {
            int i = tid + it * 256;
            int row = bm + (i >> 3);
            int rc = min(row, N - 1);
            float4 v = *(const float4*)(X + (size_t)rc * 128 + k0 + xf * 4);
            int m = i >> 3;
            sX[xf * 4 + 0][m] = v.x;
            sX[xf * 4 + 1][m] = v.y;
            sX[xf * 4 + 2][m] = v.z;
            sX[xf * 4 + 3][m] = v.w;
        }
        for (int i = tid; i < 320; i += 256) {
            int wr = i / 10;
            int wf = i - wr * 10;
            *(float4*)(&sW[wr][wf * 4]) =
                *(const float4*)(W + (size_t)(k0 + wr) * 40 + wf * 4);
        }
        __syncthreads();
        #pragma unroll
        for (int kk = 0; kk < 32; ++kk) {
            float4 a = *(const float4*)(&sX[kk][m0]);
            float av[4] = {a.x, a.y, a.z, a.w};
            #pragma unroll
            for (int c = 0; c < 5; ++c) {
                float b = sW[kk][n0 + c];
                #pragma unroll
                for (int r = 0; r < 4; ++r)
                    acc[r][c] = fmaf(av[r], b, acc[r][c]);
            }
        }
        __syncthreads();
    }
    #pragma unroll
    for (int r = 0; r < 4; ++r) {
        int row = bm + m0 + r;
        if (row < N) {
            #pragma unroll
            for (int c = 0; c < 5; ++c)
                Y[(size_t)row * 64 + n0 + c] = f2bf_rne(acc[r][c]);
        }
    }
}

// Uniform full-wave agg, F=128 bf16.  One wave per dst; lane i owns uint i
// of the 256-B row.  csr entries carry (src, w): the per-batch scalar load
// is one independent contiguous group — no dependent dinv chain.
template <bool RELU>
__global__ __launch_bounds__(256) void k_agg128(
        const ushort_t* __restrict__ XW, const int* __restrict__ rowptr,
        const int2* __restrict__ csr, const float* __restrict__ dinv,
        const float* __restrict__ bias, float* __restrict__ out, int n) {
    const int lane = threadIdx.x & 63;
    const int wv = __builtin_amdgcn_readfirstlane(threadIdx.x >> 6);  // uniform
    const int d = blockIdx.x * 4 + wv;
    if (d >= n) return;
    const uint_t* xw = (const uint_t*)XW;           // row stride 64 uints (256 B)
    float dv = dinv[d];
    float w0 = dv * dv;
    uint_t sq = xw[(size_t)d * 64 + lane];
    float2 a;
    a.x = w0 * bflo(sq);
    a.y = w0 * bfhi(sq);
    int j = rowptr[d], end = rowptr[d + 1];         // uniform
    for (; j + 8 <= end; j += 8) {
        int2 p0 = csr[j + 0], p1 = csr[j + 1], p2 = csr[j + 2], p3 = csr[j + 3];
        int2 p4 = csr[j + 4], p5 = csr[j + 5], p6 = csr[j + 6], p7 = csr[j + 7];
        uint_t u0 = xw[(size_t)p0.x * 64 + lane];
        uint_t u1 = xw[(size_t)p1.x * 64 + lane];
        uint_t u2 = xw[(size_t)p2.x * 64 + lane];
        uint_t u3 = xw[(size_t)p3.x * 64 + lane];
        uint_t u4 = xw[(size_t)p4.x * 64 + lane];
        uint_t u5 = xw[(size_t)p5.x * 64 + lane];
        uint_t u6 = xw[(size_t)p6.x * 64 + lane];
        uint_t u7 = xw[(size_t)p7.x * 64 + lane];
        float w0e = __int_as_float(p0.y), w1e = __int_as_float(p1.y);
        float w2e = __int_as_float(p2.y), w3e = __int_as_float(p3.y);
        float w4e = __int_as_float(p4.y), w5e = __int_as_float(p5.y);
        float w6e = __int_as_float(p6.y), w7e = __int_as_float(p7.y);
        a.x = fmaf(w0e, bflo(u0), a.x); a.y = fmaf(w0e, bfhi(u0), a.y);
        a.x = fmaf(w1e, bflo(u1), a.x); a.y = fmaf(w1e, bfhi(u1), a.y);
        a.x = fmaf(w2e, bflo(u2), a.x); a.y = fmaf(w2e, bfhi(u2), a.y);
        a.x = fmaf(w3e, bflo(u3), a.x); a.y = fmaf(w3e, bfhi(u3), a.y);
        a.x = fmaf(w4e, bflo(u4), a.x); a.y = fmaf(w4e, bfhi(u4), a.y);
        a.x = fmaf(w5e, bflo(u5), a.x); a.y = fmaf(w5e, bfhi(u5), a.y);
        a.x = fmaf(w6e, bflo(u6), a.x); a.y = fmaf(w6e, bfhi(u6), a.y);
        a.x = fmaf(w7e, bflo(u7), a.x); a.y = fmaf(w7e, bfhi(u7), a.y);
    }
    for (; j < end; ++j) {
        int2 p = csr[j];
        float we = __int_as_float(p.y);
        uint_t u = xw[(size_t)p.x * 64 + lane];
        a.x = fmaf(we, bflo(u), a.x);
        a.y = fmaf(we, bfhi(u), a.y);
    }
    float2 b = ((const float2*)bias)[lane];
    a.x += b.x; a.y += b.y;
    if (RELU) {
        a.x = fmaxf(a.x, 0.f);
        a.y = fmaxf(a.y, 0.f);
    }
    ((float2*)out)[(size_t)d * 64 + lane] = a;
}

// Half-wave per dst, F=40 bf16 rows padded to stride 64 (one 128-B line).
__global__ __launch_bounds__(256) void k_agg40(
        const ushort_t* __restrict__ XW, const int* __restrict__ rowptr,
        const int2* __restrict__ csr, const float* __restrict__ dinv,
        const float* __restrict__ bias, float* __restrict__ out, int n) {
    const int lane = threadIdx.x & 31;
    const int sub  = threadIdx.x >> 5;
    const int d = blockIdx.x * 8 + sub;
    if (d >= n || lane >= 20) return;
    const uint_t* xw = (const uint_t*)XW;       // row stride 32 uints
    float dv = dinv[d];
    float w0 = dv * dv;
    uint_t sq = xw[(size_t)d * 32 + lane];
    float2 a;
    a.x = w0 * bflo(sq);
    a.y = w0 * bfhi(sq);
    int j = rowptr[d], end = rowptr[d + 1];
    for (; j + 4 <= end; j += 4) {
        int2 p0 = csr[j + 0], p1 = csr[j + 1], p2 = csr[j + 2], p3 = csr[j + 3];
        uint_t u0 = xw[(size_t)p0.x * 32 + lane];
        uint_t u1 = xw[(size_t)p1.x * 32 + lane];
        uint_t u2 = xw[(size_t)p2.x * 32 + lane];
        uint_t u3 = xw[(size_t)p3.x * 32 + lane];
        float w0e = __int_as_float(p0.y), w1e = __int_as_float(p1.y);
        float w2e = __int_as_float(p2.y), w3e = __int_as_float(p3.y);
        a.x = fmaf(w0e, bflo(u0), a.x); a.y = fmaf(w0e, bfhi(u0), a.y);
        a.x = fmaf(w1e, bflo(u1), a.x); a.y = fmaf(w1e, bfhi(u1), a.y);
        a.x = fmaf(w2e, bflo(u2), a.x); a.y = fmaf(w2e, bfhi(u2), a.y);
        a.x = fmaf(w3e, bflo(u3), a.x); a.y = fmaf(w3e, bfhi(u3), a.y);
    }
    for (; j < end; ++j) {
        int2 p = csr[j];
        float we = __int_as_float(p.y);
        uint_t u = xw[(size_t)p.x * 32 + lane];
        a.x = fmaf(we, bflo(u), a.x);
        a.y = fmaf(we, bfhi(u), a.y);
    }
    float2 b = ((const float2*)bias)[lane];
    a.x += b.x; a.y += b.y;
    ((float2*)out)[(size_t)d * 20 + lane] = a;
}

static inline int cdiv(long long a, int b) { return (int)((a + b - 1) / b); }

extern "C" void kernel_launch(void* const* d_in, const int* in_sizes, int n_in,
                              void* d_out, int out_size, void* d_ws, size_t ws_size,
                              hipStream_t stream) {
    const float* x  = (const float*)d_in[0];
    const int*   ei = (const int*)d_in[1];
    const float* W1 = (const float*)d_in[2];
    const float* b1 = (const float*)d_in[3];
    const float* W2 = (const float*)d_in[4];
    const float* b2 = (const float*)d_in[5];
    const float* W3 = (const float*)d_in[6];
    const float* b3 = (const float*)d_in[7];
    float* out = (float*)d_out;

    const int N = in_sizes[0] / 128;   // 50000
    const int E = in_sizes[1] / 2;     // 800000

    char* ws = (char*)d_ws;
    int*   deg    = (int*)ws;                 ws += (size_t)N * 4;
    int*   rowptr = (int*)ws;                 ws += (size_t)(N + 1) * 4;
    int*   cursor = (int*)ws;                 ws += (size_t)N * 4;
    float* dinv   = (float*)ws;               ws += (size_t)N * 4;
    int*   bsum   = (int*)ws;                 ws += (size_t)1024 * 4;
    ws = (char*)(((uintptr_t)ws + 127) & ~(uintptr_t)127);
    int2*  csr    = (int2*)ws;                ws += (size_t)E * 8;       // 6.4 MB
    char*  bufA   = ws;                       ws += (size_t)N * 128 * 4; // bf16 XW / bf16 XW40
    float* bufB   = (float*)ws;

    const int BT = 256;
    const int nb = cdiv(N, 256);

    // CSR build (per call; no state survives between calls)
    hipMemsetAsync(deg, 0, (size_t)N * 4, stream);
    k_deg_count<<<cdiv(E, BT), BT, 0, stream>>>(ei, deg, E);
    k_bsum<<<nb, 256, 0, stream>>>(deg, bsum, N);
    k_bscan<<<1, 1024, 0, stream>>>(bsum, rowptr + N, nb);
    k_rowptr<<<nb, 256, 0, stream>>>(deg, bsum, rowptr, cursor, dinv, N);
    k_fill<<<cdiv(E, BT) * 8, 256, 0, stream>>>(ei, cursor, dinv, csr, E, N);

    // layer 1
    k_gemm128<<<cdiv(N, 128), 256, 0, stream>>>(x, W1, (ushort_t*)bufA, N);
    k_agg128<true><<<cdiv(N, 4), 256, 0, stream>>>((const ushort_t*)bufA, rowptr, csr, dinv, b1, bufB, N);
    // layer 2
    k_gemm128<<<cdiv(N, 128), 256, 0, stream>>>(bufB, W2, (ushort_t*)bufA, N);
    k_agg128<true><<<cdiv(N, 4), 256, 0, stream>>>((const ushort_t*)bufA, rowptr, csr, dinv, b2, bufB, N);
    // layer 3 (bf16 staged, rows padded to one 128-B line)
    k_gemm40<<<cdiv(N, 128), 256, 0, stream>>>(bufB, W3, (ushort_t*)bufA, N);
    k_agg40<<<cdiv(N, 8), 256, 0, stream>>>((const ushort_t*)bufA, rowptr, csr, dinv, b3, out, N);
}